// Round 17
// baseline (226.528 us; speedup 1.0000x reference)
//
#include <hip/hip_runtime.h>
#include <math.h>

#define B_ 2
#define T_ 2048
#define C_ 1024
#define H_ 16
#define HD_ 64
#define M_ (B_*T_)

typedef _Float16 half2v __attribute__((ext_vector_type(2)));
typedef _Float16 half4v __attribute__((ext_vector_type(4)));
typedef _Float16 half8v __attribute__((ext_vector_type(8)));
typedef float f32x4 __attribute__((ext_vector_type(4)));

#define GLD_LDS(gp, lp) \
  __builtin_amdgcn_global_load_lds( \
      (const __attribute__((address_space(1))) void*)(gp), \
      (__attribute__((address_space(3))) void*)(lp), 16, 0, 0)

// ---------------------------------------------------------------------------
// Fused prep: fp32->f16 cast of x (blocks 0..2047, coalesced 2-chunk/thread),
// 4 weight transposes (blocks 2048..6143), bias concat (blocks 6144..6155).
// ---------------------------------------------------------------------------
__global__ __launch_bounds__(256) void prep_kernel(
    const float* __restrict__ x,
    const float* __restrict__ Wq, const float* __restrict__ Wk,
    const float* __restrict__ Wv, const float* __restrict__ Wo,
    const float* __restrict__ bq, const float* __restrict__ bk,
    const float* __restrict__ bv,
    _Float16* __restrict__ xh, _Float16* __restrict__ Wt3,
    _Float16* __restrict__ Wot, float* __restrict__ b3)
{
  __shared__ float tile[32][33];
  const int blk = blockIdx.x, thr = threadIdx.x;
  if (blk < 2048) {
    int base = blk * 512;
    float4 v0 = ((const float4*)x)[base + thr];
    float4 v1 = ((const float4*)x)[base + 256 + thr];
    half4v h0, h1;
    h0[0] = (_Float16)v0.x; h0[1] = (_Float16)v0.y;
    h0[2] = (_Float16)v0.z; h0[3] = (_Float16)v0.w;
    h1[0] = (_Float16)v1.x; h1[1] = (_Float16)v1.y;
    h1[2] = (_Float16)v1.z; h1[3] = (_Float16)v1.w;
    ((half4v*)xh)[base + thr] = h0;
    ((half4v*)xh)[base + 256 + thr] = h1;
  } else if (blk < 6144) {
    int zz = (blk - 2048) >> 10;      // which W
    int bxy = (blk - 2048) & 1023;
    const float* W; _Float16* Wt;
    switch (zz) {
      case 0:  W = Wq; Wt = Wt3; break;
      case 1:  W = Wk; Wt = Wt3 + (size_t)1024 * 1024; break;
      case 2:  W = Wv; Wt = Wt3 + (size_t)2048 * 1024; break;
      default: W = Wo; Wt = Wot; break;
    }
    const int n0 = (bxy & 31) * 32, k0 = (bxy >> 5) * 32;
    const int tx = thr & 31, ty = thr >> 5;  // 32 x 8
#pragma unroll
    for (int r = 0; r < 4; r++) {
      int k = ty + r * 8;
      tile[k][tx] = W[(size_t)(k0 + k) * C_ + n0 + tx];
    }
    __syncthreads();
#pragma unroll
    for (int r = 0; r < 4; r++) {
      int n = ty + r * 8;
      Wt[(size_t)(n0 + n) * C_ + k0 + tx] = (_Float16)tile[tx][n];
    }
  } else {
    int i = (blk - 6144) * 256 + thr;  // 0..3071
    const float* s = (i < 1024) ? bq : ((i < 2048) ? bk : bv);
    b3[i] = s[i & 1023];
  }
}

// ---------------------------------------------------------------------------
// f16 MFMA GEMM: Out[M,N] = A[M,1024] @ Wt[N,1024]^T + bias.  (r11 exact)
// BK=64 via two 32-wide K-slice buffers per barrier pair; LDS 32 KB;
// global_load_lds staging; bijective XCD swizzle (T1).
// EPI 0: fused QKV epilogue (Q scaled, K plain, V packed to V^T).
// EPI 1: fp32 out + bias (of).
// ---------------------------------------------------------------------------
template <int BM, int BN, int EPI, int GX, int GY>
__global__ __launch_bounds__(256) void gemm_f16_kernel(
    const _Float16* __restrict__ A, const _Float16* __restrict__ Bw,
    const float* __restrict__ bias,
    _Float16* __restrict__ o0, _Float16* __restrict__ o1,
    _Float16* __restrict__ o2, float* __restrict__ of)
{
  constexpr int FM = BM / 32, FN = BN / 32;
  constexpr int NWG = GX * GY, CPX = NWG / 8;   // GX*GY divisible by 8
  __shared__ __align__(16) _Float16 As[2 * BM * 32];
  __shared__ __align__(16) _Float16 Bs[2 * BN * 32];
  const int t = threadIdx.x;
  const int w = t >> 6, lane = t & 63, l15 = lane & 15, quad = lane >> 4;
  const int wm = (w & 1) * (BM / 2), wn = (w >> 1) * (BN / 2);
  const int lin = blockIdx.x + GX * blockIdx.y;
  const int swz = (lin & 7) * CPX + (lin >> 3);
  const int bxs = swz % GX, bys = swz / GX;
  const int bm = bys * BM, bn = bxs * BN;
  const int lrow = lane >> 2, lcol = (lane & 3) * 8;  // staging: 16 rows/call

  f32x4 acc[FM][FN];
#pragma unroll
  for (int i = 0; i < FM; i++)
#pragma unroll
    for (int j = 0; j < FN; j++) acc[i][j] = (f32x4){0.f, 0.f, 0.f, 0.f};

  for (int k0 = 0; k0 < 1024; k0 += 64) {
#pragma unroll
    for (int hf = 0; hf < 2; hf++) {
#pragma unroll
      for (int i = 0; i < BM / 64; i++) {
        int ca = w + 4 * i;
        int row = ca * 16 + lrow;
        GLD_LDS(A + (size_t)(bm + row) * 1024 + k0 + hf * 32 + lcol,
                As + hf * BM * 32 + ca * 512);
      }
#pragma unroll
      for (int i = 0; i < BN / 64; i++) {
        int cb = w + 4 * i;
        int row = cb * 16 + lrow;
        GLD_LDS(Bw + (size_t)(bn + row) * 1024 + k0 + hf * 32 + lcol,
                Bs + hf * BN * 32 + cb * 512);
      }
    }
    __syncthreads();

#pragma unroll
    for (int hf = 0; hf < 2; hf++) {
      half8v af[FM], bf[FN];
#pragma unroll
      for (int mt = 0; mt < FM; mt++)
        af[mt] = *(const half8v*)(As + hf * BM * 32 +
                                  (wm + mt * 16 + l15) * 32 + quad * 8);
#pragma unroll
      for (int nt = 0; nt < FN; nt++)
        bf[nt] = *(const half8v*)(Bs + hf * BN * 32 +
                                  (wn + nt * 16 + l15) * 32 + quad * 8);
#pragma unroll
      for (int mt = 0; mt < FM; mt++)
#pragma unroll
        for (int nt = 0; nt < FN; nt++)
          acc[mt][nt] = __builtin_amdgcn_mfma_f32_16x16x32_f16(
              af[mt], bf[nt], acc[mt][nt], 0, 0, 0);
    }
    __syncthreads();
  }

  // Epilogue. C/D layout: col = l15 (n), row = quad*4 + r (m).
#pragma unroll
  for (int mt = 0; mt < FM; mt++)
#pragma unroll
    for (int nt = 0; nt < FN; nt++) {
      int n = bn + wn + nt * 16 + l15;
      float bv = bias[n];
      if (EPI == 0 && bn >= 2048) {
        int dg = n - 2048;
        int hh = dg >> 6, hd = dg & 63;
        int m0 = bm + wm + mt * 16 + quad * 4;
        int bb = m0 >> 11, tt = m0 & 2047;
        half2v p01 = __builtin_bit_cast(half2v,
            __builtin_amdgcn_cvt_pkrtz(acc[mt][nt][0] + bv, acc[mt][nt][1] + bv));
        half2v p23 = __builtin_bit_cast(half2v,
            __builtin_amdgcn_cvt_pkrtz(acc[mt][nt][2] + bv, acc[mt][nt][3] + bv));
        half4v pk = __builtin_shufflevector(p01, p23, 0, 1, 2, 3);
        *(half4v*)(o2 + (((size_t)(bb * H_ + hh) * 64 + hd) * 2048 + tt)) = pk;
      } else {
#pragma unroll
        for (int r = 0; r < 4; r++) {
          int m = bm + wm + mt * 16 + quad * 4 + r;
          float v = acc[mt][nt][r] + bv;
          if (EPI == 0) {
            if (bn < 1024) {
              o0[(size_t)m * 1024 + n] = (_Float16)(v * 0.180336884f);
            } else {
              o1[(size_t)m * 1024 + (n - 1024)] = (_Float16)v;    // K
            }
          } else {
            of[(size_t)m * 1024 + n] = v;
          }
        }
      }
    }
}

// ---------------------------------------------------------------------------
// MFMA flash attention, split-T + 32KB XOR-swizzled LDS (r17).
// Residency law (from r0/r1/r2/r3/r16 occupancy data): LDS alloc rounds UP
// TO A POWER OF TWO -- 34.3 KB allocated 64 KB, capping 512-thr blocks at
// 2/CU all session. Fix: UNPADDED Ks[128][64] + Vs[64][128] = exactly
// 32,768 B, bank conflicts handled by the G4 XOR swizzle byte^=(row&7)<<4
// (reg-staged writes + reads use the same involution; K-read 2-way, V-read
// 2-way = free). 4 blocks x 512 thr = 32 waves/CU (thread-capped max).
// SPLIT=1 supplies the grid (1024 blocks = 4/CU): half keys per block,
// unnormalized f32 partials + combine (r16 machinery, absmax-verified).
// SPLIT=0 fallback: full 2048 keys, normalized f16 out.
// Loop body otherwise byte-identical to the proven V15 frame (PV x32
// dual-half4v, XCD swizzle, setprio, base-2 softmax).
// ---------------------------------------------------------------------------
template <int SPLIT>
__global__ __launch_bounds__(512) void attn_f16_kernel(
    const _Float16* __restrict__ Qh, const _Float16* __restrict__ Kh,
    const _Float16* __restrict__ Vt, _Float16* __restrict__ Yh,
    float* __restrict__ Op, float2* __restrict__ mlp)
{
  __shared__ __align__(16) _Float16 Ks[128 * 64];   // 16,384 B, XOR-swizzled
  __shared__ __align__(16) _Float16 Vs[64 * 128];   // 16,384 B, XOR-swizzled
  const int t = threadIdx.x;
  const int w = t >> 6, lane = t & 63, l15 = lane & 15, quad = lane >> 4;
  const int lin = blockIdx.x + 16 * blockIdx.y + 256 * blockIdx.z;
  const int swz = SPLIT ? ((lin & 7) * 128 + (lin >> 3))
                        : ((lin & 7) * 64 + (lin >> 3));
  const int qt = swz & 15, h = (swz >> 4) & 15;
  const int zz = swz >> 8;                    // SPLIT: b*2+half; else b
  const int b = SPLIT ? (zz >> 1) : zz;
  const int half = SPLIT ? (zz & 1) : 0;
  const int qg = qt * 128 + w * 16 + l15;
  const size_t qoff = ((size_t)(b * T_ + qg)) * C_ + h * HD_;

  half8v qf[2];
  qf[0] = *(const half8v*)(Qh + qoff + quad * 8);
  qf[1] = *(const half8v*)(Qh + qoff + 32 + quad * 8);

  f32x4 o[4];
#pragma unroll
  for (int i = 0; i < 4; i++) o[i] = (f32x4){0.f, 0.f, 0.f, 0.f};
  float m_run = -INFINITY, l_run = 0.f;

  const size_t kbase = ((size_t)b * T_) * C_ + h * HD_;
  const size_t vbase = ((size_t)(b * H_ + h)) * HD_ * 2048;

  // XOR-swizzle constants: the K-read/V-read XOR depends only on l15&7.
  const int sx = (l15 & 7) << 4;

  const int kt_lo = SPLIT ? half * 1024 : 0;
  const int kt_hi = SPLIT ? kt_lo + 1024 : T_;

  for (int kt0 = kt_lo; kt0 < kt_hi; kt0 += 128) {
    // Stage K: 128 keys x 64 d = 1024 16-B chunks (2/thread), swizzled.
#pragma unroll
    for (int i = 0; i < 2; i++) {
      int slot = t + i * 512;          // 0..1023
      int row = slot >> 3, cp = slot & 7;
      int off = (row * 128 + cp * 16) ^ ((row & 7) << 4);
      *(uint4*)((char*)Ks + off) =
          *(const uint4*)(Kh + kbase + (size_t)(kt0 + row) * C_ + cp * 8);
    }
    // Stage V^T: 64 d x 128 t = 1024 16-B chunks (2/thread), swizzled.
#pragma unroll
    for (int i = 0; i < 2; i++) {
      int slot = t + i * 512;          // 0..1023
      int row = slot >> 4, cp = slot & 15;
      int off = (row * 256 + cp * 16) ^ ((row & 7) << 4);
      *(uint4*)((char*)Vs + off) =
          *(const uint4*)(Vt + vbase + (size_t)row * 2048 + kt0 + cp * 8);
    }
    __syncthreads();

    // S^T tiles: 8 key-tiles x 2 d-steps of 16x16x32. key&7 == l15&7.
    f32x4 s[8];
    __builtin_amdgcn_s_setprio(1);
#pragma unroll
    for (int kt = 0; kt < 8; kt++) {
      s[kt] = (f32x4){0.f, 0.f, 0.f, 0.f};
      int key = kt * 16 + l15;
#pragma unroll
      for (int ks = 0; ks < 2; ks++) {
        int off = (key * 128 + (ks * 4 + quad) * 16) ^ sx;
        half8v kf = *(const half8v*)((char*)Ks + off);
        s[kt] = __builtin_amdgcn_mfma_f32_16x16x32_f16(kf, qf[ks], s[kt], 0, 0, 0);
      }
    }
    __builtin_amdgcn_s_setprio(0);

    // Online softmax (base-2) over the 128 keys, per q column = l15.
    float tmax = -INFINITY;
#pragma unroll
    for (int kt = 0; kt < 8; kt++)
#pragma unroll
      for (int r = 0; r < 4; r++) tmax = fmaxf(tmax, s[kt][r]);
    tmax = fmaxf(tmax, __shfl_xor(tmax, 16));
    tmax = fmaxf(tmax, __shfl_xor(tmax, 32));
    float mnew = fmaxf(m_run, tmax);
    float alpha = __builtin_amdgcn_exp2f(m_run - mnew);

    float psum = 0.f;
    half4v pf[8];
#pragma unroll
    for (int kt = 0; kt < 8; kt++) {
      float p0 = __builtin_amdgcn_exp2f(s[kt][0] - mnew);
      float p1 = __builtin_amdgcn_exp2f(s[kt][1] - mnew);
      float p2 = __builtin_amdgcn_exp2f(s[kt][2] - mnew);
      float p3 = __builtin_amdgcn_exp2f(s[kt][3] - mnew);
      psum += (p0 + p1) + (p2 + p3);
      half2v pk01 = __builtin_bit_cast(half2v, __builtin_amdgcn_cvt_pkrtz(p0, p1));
      half2v pk23 = __builtin_bit_cast(half2v, __builtin_amdgcn_cvt_pkrtz(p2, p3));
      pf[kt] = __builtin_shufflevector(pk01, pk23, 0, 1, 2, 3);
    }
    psum += __shfl_xor(psum, 16);
    psum += __shfl_xor(psum, 32);
    l_run = l_run * alpha + psum;
    m_run = mnew;
#pragma unroll
    for (int dt = 0; dt < 4; dt++) o[dt] *= alpha;

    // PV: o^T[d][q] += V^T x P, 4 d-tiles x 4 key-groups of 16x16x32.
    // d&7 == l15&7; 8-B reads keep bits 0-3, XOR flips bits 4-6 only.
    __builtin_amdgcn_s_setprio(1);
#pragma unroll
    for (int dt = 0; dt < 4; dt++) {
      int d = dt * 16 + l15;
#pragma unroll
      for (int p = 0; p < 4; p++) {
        int off0 = (d * 256 + p * 64 + quad * 8) ^ sx;
        int off1 = (d * 256 + p * 64 + 32 + quad * 8) ^ sx;
        half4v v0 = *(const half4v*)((char*)Vs + off0);
        half4v v1 = *(const half4v*)((char*)Vs + off1);
        half8v vf = __builtin_shufflevector(v0, v1, 0, 1, 2, 3, 4, 5, 6, 7);
        half8v pf8 = __builtin_shufflevector(pf[2 * p], pf[2 * p + 1],
                                             0, 1, 2, 3, 4, 5, 6, 7);
        o[dt] = __builtin_amdgcn_mfma_f32_16x16x32_f16(vf, pf8, o[dt], 0, 0, 0);
      }
    }
    __builtin_amdgcn_s_setprio(0);
    __syncthreads();
  }

  if (SPLIT) {
    const int row = b * T_ + qg;
    float* op = Op + (size_t)half * 4194304 + (size_t)row * 1024 + h * HD_;
#pragma unroll
    for (int dt = 0; dt < 4; dt++) {
      float4 pv;
      pv.x = o[dt][0]; pv.y = o[dt][1]; pv.z = o[dt][2]; pv.w = o[dt][3];
      *(float4*)(op + dt * 16 + quad * 4) = pv;
    }
    if (quad == 0) {
      float2 ml; ml.x = m_run; ml.y = l_run;
      mlp[(size_t)half * 65536 + (size_t)row * 16 + h] = ml;
    }
  } else {
    float inv = 1.0f / l_run;
#pragma unroll
    for (int dt = 0; dt < 4; dt++) {
      half4v yv;
#pragma unroll
      for (int r = 0; r < 4; r++) yv[r] = (_Float16)(o[dt][r] * inv);
      *(half4v*)(Yh + qoff + dt * 16 + quad * 4) = yv;
    }
  }
}

// ---------------------------------------------------------------------------
// Combine the two key-half partials: y = (o0*a0 + o1*a1) / (l0*a0 + l1*a1),
// a_i = 2^(m_i - max(m0,m1)). 2048 blocks x 256 thr; 8 channels/thread.
// ---------------------------------------------------------------------------
__global__ __launch_bounds__(256) void attn_combine(
    const float* __restrict__ Op, const float2* __restrict__ mlp,
    _Float16* __restrict__ Yh)
{
  const int idx = blockIdx.x * 256 + threadIdx.x;   // 0..524287
  const int row = idx >> 7;                          // 0..4095
  const int c0  = (idx & 127) * 8;                   // channel group
  const int h   = c0 >> 6;
  float2 ml0 = mlp[(size_t)row * 16 + h];
  float2 ml1 = mlp[(size_t)65536 + (size_t)row * 16 + h];
  float M  = fmaxf(ml0.x, ml1.x);
  float a0 = __builtin_amdgcn_exp2f(ml0.x - M);
  float a1 = __builtin_amdgcn_exp2f(ml1.x - M);
  float inv = 1.0f / (ml0.y * a0 + ml1.y * a1);
  const float4* p0 = (const float4*)(Op + (size_t)row * 1024 + c0);
  const float4* p1 = (const float4*)(Op + (size_t)4194304 + (size_t)row * 1024 + c0);
  half8v y;
#pragma unroll
  for (int i = 0; i < 2; i++) {
    float4 u = p0[i], v = p1[i];
    y[i * 4 + 0] = (_Float16)((u.x * a0 + v.x * a1) * inv);
    y[i * 4 + 1] = (_Float16)((u.y * a0 + v.y * a1) * inv);
    y[i * 4 + 2] = (_Float16)((u.z * a0 + v.z * a1) * inv);
    y[i * 4 + 3] = (_Float16)((u.w * a0 + v.w * a1) * inv);
  }
  *(half8v*)(Yh + (size_t)row * 1024 + c0) = y;
}

// ---------------------------------------------------------------------------
extern "C" void kernel_launch(void* const* d_in, const int* in_sizes, int n_in,
                              void* d_out, int out_size, void* d_ws, size_t ws_size,
                              hipStream_t stream) {
  const float* x  = (const float*)d_in[0];
  const float* Wq = (const float*)d_in[1];
  const float* bq = (const float*)d_in[2];
  const float* Wk = (const float*)d_in[3];
  const float* bk = (const float*)d_in[4];
  const float* Wv = (const float*)d_in[5];
  const float* bv = (const float*)d_in[6];
  const float* Wo = (const float*)d_in[7];
  const float* bo = (const float*)d_in[8];
  float* out = (float*)d_out;

  // Workspace carve-up (bytes). Each f16 plane M_*C_ = 8 MB.
  char* ws = (char*)d_ws;
  _Float16* xh   = (_Float16*)(ws);                        // 8 MB
  _Float16* Qh   = (_Float16*)(ws + (((size_t)8)  << 20)); // 8 MB
  _Float16* Kh   = (_Float16*)(ws + (((size_t)16) << 20)); // 8 MB
  _Float16* Vt   = (_Float16*)(ws + (((size_t)24) << 20)); // 8 MB  [b,h,d,t]
  _Float16* Yh   = (_Float16*)(ws + (((size_t)32) << 20)); // 8 MB
  _Float16* Wt3  = (_Float16*)(ws + (((size_t)40) << 20)); // 6 MB  [3072][1024]
  _Float16* Wot  = (_Float16*)(ws + (((size_t)46) << 20)); // 2 MB  [1024][1024]
  float*    b3   = (float*)   (ws + (((size_t)48) << 20)); // 12 KB
  // Split-attention partials (guarded): Op = 2x16 MB f32 @56 MB, ml = 1 MB.
  float*    Op   = (float*)   (ws + (((size_t)56) << 20)); // 32 MB
  float2*   mlp  = (float2*)  (ws + (((size_t)88) << 20)); // 1 MB
  const bool split_ok = ws_size >= (((size_t)90) << 20);

  prep_kernel<<<6156, 256, 0, stream>>>(x, Wq, Wk, Wv, Wo, bq, bk, bv,
                                        xh, Wt3, Wot, b3);

  // Fused QKV projection: [4096,1024] @ [1024,3072] -> Q,K (f16) + V^T (f16).
  gemm_f16_kernel<128, 128, 0, 24, 32><<<dim3(24, 32), 256, 0, stream>>>(
      xh, Wt3, b3, Qh, Kh, Vt, nullptr);

  if (split_ok) {
    attn_f16_kernel<1><<<dim3(T_ / 128, H_, 2 * B_), 512, 0, stream>>>(
        Qh, Kh, Vt, Yh, Op, mlp);
    attn_combine<<<2048, 256, 0, stream>>>(Op, mlp, Yh);
  } else {
    attn_f16_kernel<0><<<dim3(T_ / 128, H_, B_), 512, 0, stream>>>(
        Qh, Kh, Vt, Yh, nullptr, nullptr);
  }

  // Output projection: Yh @ Wot^T + bo -> fp32 out.
  gemm_f16_kernel<64, 128, 1, 8, 64><<<dim3(8, 64), 256, 0, stream>>>(
      Yh, Wot, bo, nullptr, nullptr, nullptr, out);
}

// Round 18
// 198.905 us; speedup vs baseline: 1.1389x; 1.1389x over previous
//
#include <hip/hip_runtime.h>
#include <math.h>

#define B_ 2
#define T_ 2048
#define C_ 1024
#define H_ 16
#define HD_ 64
#define M_ (B_*T_)

typedef _Float16 half2v __attribute__((ext_vector_type(2)));
typedef _Float16 half4v __attribute__((ext_vector_type(4)));
typedef _Float16 half8v __attribute__((ext_vector_type(8)));
typedef float f32x4 __attribute__((ext_vector_type(4)));

#define GLD_LDS(gp, lp) \
  __builtin_amdgcn_global_load_lds( \
      (const __attribute__((address_space(1))) void*)(gp), \
      (__attribute__((address_space(3))) void*)(lp), 16, 0, 0)

// ---------------------------------------------------------------------------
// Fused prep: fp32->f16 cast of x (blocks 0..4095), 4 weight transposes
// (blocks 4096..8191), bias concat (blocks 8192..8203). One launch.
// ---------------------------------------------------------------------------
__global__ __launch_bounds__(256) void prep_kernel(
    const float* __restrict__ x,
    const float* __restrict__ Wq, const float* __restrict__ Wk,
    const float* __restrict__ Wv, const float* __restrict__ Wo,
    const float* __restrict__ bq, const float* __restrict__ bk,
    const float* __restrict__ bv,
    _Float16* __restrict__ xh, _Float16* __restrict__ Wt3,
    _Float16* __restrict__ Wot, float* __restrict__ b3)
{
  __shared__ float tile[32][33];
  const int blk = blockIdx.x, thr = threadIdx.x;
  if (blk < 4096) {
    int i = blk * 256 + thr;
    float4 v = ((const float4*)x)[i];
    half4v h; h[0] = (_Float16)v.x; h[1] = (_Float16)v.y;
    h[2] = (_Float16)v.z; h[3] = (_Float16)v.w;
    ((half4v*)xh)[i] = h;
  } else if (blk < 8192) {
    int zz = (blk - 4096) >> 10;      // which W
    int bxy = (blk - 4096) & 1023;
    const float* W; _Float16* Wt;
    switch (zz) {
      case 0:  W = Wq; Wt = Wt3; break;
      case 1:  W = Wk; Wt = Wt3 + (size_t)1024 * 1024; break;
      case 2:  W = Wv; Wt = Wt3 + (size_t)2048 * 1024; break;
      default: W = Wo; Wt = Wot; break;
    }
    const int n0 = (bxy & 31) * 32, k0 = (bxy >> 5) * 32;
    const int tx = thr & 31, ty = thr >> 5;  // 32 x 8
#pragma unroll
    for (int r = 0; r < 4; r++) {
      int k = ty + r * 8;
      tile[k][tx] = W[(size_t)(k0 + k) * C_ + n0 + tx];
    }
    __syncthreads();
#pragma unroll
    for (int r = 0; r < 4; r++) {
      int n = ty + r * 8;
      Wt[(size_t)(n0 + n) * C_ + k0 + tx] = (_Float16)tile[tx][n];
    }
  } else {
    int i = (blk - 8192) * 256 + thr;  // 0..3071
    const float* s = (i < 1024) ? bq : ((i < 2048) ? bk : bv);
    b3[i] = s[i & 1023];
  }
}

// ---------------------------------------------------------------------------
// f16 MFMA GEMM: Out[M,N] = A[M,1024] @ Wt[N,1024]^T + bias.
// r11: effective BK=64 via TWO 32-wide K-slice buffers per barrier pair:
// 8 GLD -> barrier -> 32 MFMA -> barrier, 16 iterations. Row stride stays
// 64 B (2-way LDS conflict = free). LDS 32 KB. A staged via global_load_lds
// (m151 + r12's AF32 experiment: reg-staging costs ~26%).
// r10: bijective XCD swizzle (T1) -- contiguous by-chunks per XCD.
// EPI 0: fused QKV epilogue. Q (scaled 0.125*log2e) and K: plain 2-B stores.
// V: packed 8-B stores to V^T.  EPI 1: fp32 out + bias (of).
// ---------------------------------------------------------------------------
template <int BM, int BN, int EPI, int GX, int GY>
__global__ __launch_bounds__(256) void gemm_f16_kernel(
    const _Float16* __restrict__ A, const _Float16* __restrict__ Bw,
    const float* __restrict__ bias,
    _Float16* __restrict__ o0, _Float16* __restrict__ o1,
    _Float16* __restrict__ o2, float* __restrict__ of)
{
  constexpr int FM = BM / 32, FN = BN / 32;
  constexpr int NWG = GX * GY, CPX = NWG / 8;   // GX*GY divisible by 8
  __shared__ __align__(16) _Float16 As[2 * BM * 32];
  __shared__ __align__(16) _Float16 Bs[2 * BN * 32];
  const int t = threadIdx.x;
  const int w = t >> 6, lane = t & 63, l15 = lane & 15, quad = lane >> 4;
  const int wm = (w & 1) * (BM / 2), wn = (w >> 1) * (BN / 2);
  // XCD-aware bijective remap of the linear block id.
  const int lin = blockIdx.x + GX * blockIdx.y;
  const int swz = (lin & 7) * CPX + (lin >> 3);
  const int bxs = swz % GX, bys = swz / GX;
  const int bm = bys * BM, bn = bxs * BN;
  const int lrow = lane >> 2, lcol = (lane & 3) * 8;  // staging: 16 rows/call

  f32x4 acc[FM][FN];
#pragma unroll
  for (int i = 0; i < FM; i++)
#pragma unroll
    for (int j = 0; j < FN; j++) acc[i][j] = (f32x4){0.f, 0.f, 0.f, 0.f};

  for (int k0 = 0; k0 < 1024; k0 += 64) {
#pragma unroll
    for (int hf = 0; hf < 2; hf++) {
#pragma unroll
      for (int i = 0; i < BM / 64; i++) {
        int ca = w + 4 * i;
        int row = ca * 16 + lrow;
        GLD_LDS(A + (size_t)(bm + row) * 1024 + k0 + hf * 32 + lcol,
                As + hf * BM * 32 + ca * 512);
      }
#pragma unroll
      for (int i = 0; i < BN / 64; i++) {
        int cb = w + 4 * i;
        int row = cb * 16 + lrow;
        GLD_LDS(Bw + (size_t)(bn + row) * 1024 + k0 + hf * 32 + lcol,
                Bs + hf * BN * 32 + cb * 512);
      }
    }
    __syncthreads();

#pragma unroll
    for (int hf = 0; hf < 2; hf++) {
      half8v af[FM], bf[FN];
#pragma unroll
      for (int mt = 0; mt < FM; mt++)
        af[mt] = *(const half8v*)(As + hf * BM * 32 +
                                  (wm + mt * 16 + l15) * 32 + quad * 8);
#pragma unroll
      for (int nt = 0; nt < FN; nt++)
        bf[nt] = *(const half8v*)(Bs + hf * BN * 32 +
                                  (wn + nt * 16 + l15) * 32 + quad * 8);
#pragma unroll
      for (int mt = 0; mt < FM; mt++)
#pragma unroll
        for (int nt = 0; nt < FN; nt++)
          acc[mt][nt] = __builtin_amdgcn_mfma_f32_16x16x32_f16(
              af[mt], bf[nt], acc[mt][nt], 0, 0, 0);
    }
    __syncthreads();
  }

  // Epilogue. C/D layout: col = l15 (n), row = quad*4 + r (m).
#pragma unroll
  for (int mt = 0; mt < FM; mt++)
#pragma unroll
    for (int nt = 0; nt < FN; nt++) {
      int n = bn + wn + nt * 16 + l15;
      float bv = bias[n];
      if (EPI == 0 && bn >= 2048) {
        // V region: pack r=0..3 (consecutive t) -> one 8-B store to V^T.
        int dg = n - 2048;
        int hh = dg >> 6, hd = dg & 63;
        int m0 = bm + wm + mt * 16 + quad * 4;
        int bb = m0 >> 11, tt = m0 & 2047;
        half2v p01 = __builtin_bit_cast(half2v,
            __builtin_amdgcn_cvt_pkrtz(acc[mt][nt][0] + bv, acc[mt][nt][1] + bv));
        half2v p23 = __builtin_bit_cast(half2v,
            __builtin_amdgcn_cvt_pkrtz(acc[mt][nt][2] + bv, acc[mt][nt][3] + bv));
        half4v pk = __builtin_shufflevector(p01, p23, 0, 1, 2, 3);
        *(half4v*)(o2 + (((size_t)(bb * H_ + hh) * 64 + hd) * 2048 + tt)) = pk;
      } else {
#pragma unroll
        for (int r = 0; r < 4; r++) {
          int m = bm + wm + mt * 16 + quad * 4 + r;
          float v = acc[mt][nt][r] + bv;
          if (EPI == 0) {
            if (bn < 1024) {
              // Q pre-scaled by 0.125 * log2(e) for base-2 softmax.
              o0[(size_t)m * 1024 + n] = (_Float16)(v * 0.180336884f);
            } else {
              o1[(size_t)m * 1024 + (n - 1024)] = (_Float16)v;    // K
            }
          } else {
            of[(size_t)m * 1024 + n] = v;
          }
        }
      }
    }
}

// ---------------------------------------------------------------------------
// MFMA flash attention (no mask, per reference). Grid (T/128, H, B), 512 thr.
// V15 frame (session best: 61.8-62.3 us measured r6/r10/r11/r15):
//  (a') PV 16x16x32 via dual-half4v V-operand, unpermuted S^T (r6).
//  (b) bijective XCD swizzle (r5: FETCH 69.7 -> 12.3 MB).
//  (c) s_setprio(1) around MFMA clusters (T5).
// Closed-out by measurement: T14 async/issue-early (r2/r3/r7/r8), T13/T17
// (r9), key-permuted PV (r5: 9x bank conflicts), split-T (r16: 1024 blocks
// still 2/CU -> two passes; r17: 32KB LDS pushed VGPR 48->68 over the
// 64-VGPR wave-cap AND 4x'd bank conflicts). Residency is jointly capped
// by LDS granularity + VGPR<=64 + conflict-free layout -- never satisfied
// together in this frame. Remaining 40% stall = barrier convoy at 2
// blocks/CU; not addressable with measured-positive techniques.
// LDS: Ks[128][68] + Vs[64][132] = 34.3 KB. Base-2 softmax.
// ---------------------------------------------------------------------------
__global__ __launch_bounds__(512) void attn_f16_kernel(
    const _Float16* __restrict__ Qh, const _Float16* __restrict__ Kh,
    const _Float16* __restrict__ Vt, _Float16* __restrict__ Yh)
{
  __shared__ __align__(16) _Float16 Ks[128 * 68];   // [key][d], 136-B rows
  __shared__ __align__(16) _Float16 Vs[64 * 132];   // [d][t], 264-B rows
  const int t = threadIdx.x;
  const int w = t >> 6, lane = t & 63, l15 = lane & 15, quad = lane >> 4;
  // XCD-aware bijective remap of the 512 linear block ids (x fastest):
  // swz = (lin%8)*64 + lin/8 -> 64-consecutive-work chunks per XCD,
  // each chunk = 4 complete (b,h) groups (their K/V stay in one L2).
  const int lin = blockIdx.x + 16 * blockIdx.y + 256 * blockIdx.z;
  const int swz = (lin & 7) * 64 + (lin >> 3);
  const int qt = swz & 15, h = (swz >> 4) & 15, b = swz >> 8;
  const int qg = qt * 128 + w * 16 + l15;
  const size_t qoff = ((size_t)(b * T_ + qg)) * C_ + h * HD_;

  half8v qf[2];
  qf[0] = *(const half8v*)(Qh + qoff + quad * 8);
  qf[1] = *(const half8v*)(Qh + qoff + 32 + quad * 8);

  f32x4 o[4];
#pragma unroll
  for (int i = 0; i < 4; i++) o[i] = (f32x4){0.f, 0.f, 0.f, 0.f};
  float m_run = -INFINITY, l_run = 0.f;

  const size_t kbase = ((size_t)b * T_) * C_ + h * HD_;
  const size_t vbase = ((size_t)(b * H_ + h)) * HD_ * 2048;

  for (int kt0 = 0; kt0 < T_; kt0 += 128) {
    // Stage K: 128 keys x 64 d = 1024 16-B chunks (2 per thread).
#pragma unroll
    for (int i = 0; i < 2; i++) {
      int slot = t + i * 512;          // 0..1023
      int row = slot >> 3, cp = slot & 7;
      *(uint4*)((char*)Ks + row * 136 + cp * 16) =
          *(const uint4*)(Kh + kbase + (size_t)(kt0 + row) * C_ + cp * 8);
    }
    // Stage V^T: 64 d x 128 t = 1024 16-B chunks (2 per thread).
#pragma unroll
    for (int i = 0; i < 2; i++) {
      int slot = t + i * 512;          // 0..1023
      int row = slot >> 4, cp = slot & 15;
      *(uint4*)((char*)Vs + row * 264 + cp * 16) =
          *(const uint4*)(Vt + vbase + (size_t)row * 2048 + kt0 + cp * 8);
    }
    __syncthreads();

    // S^T tiles: 8 key-tiles x 2 d-steps of 16x16x32 (unpermuted).
    f32x4 s[8];
    __builtin_amdgcn_s_setprio(1);
#pragma unroll
    for (int kt = 0; kt < 8; kt++) {
      s[kt] = (f32x4){0.f, 0.f, 0.f, 0.f};
      int key = kt * 16 + l15;
#pragma unroll
      for (int ks = 0; ks < 2; ks++) {
        half8v kf = *(const half8v*)((char*)Ks + key * 136 + (ks * 4 + quad) * 16);
        s[kt] = __builtin_amdgcn_mfma_f32_16x16x32_f16(kf, qf[ks], s[kt], 0, 0, 0);
      }
    }
    __builtin_amdgcn_s_setprio(0);

    // Online softmax (base-2) over the 128 keys, per q column = l15.
    float tmax = -INFINITY;
#pragma unroll
    for (int kt = 0; kt < 8; kt++)
#pragma unroll
      for (int r = 0; r < 4; r++) tmax = fmaxf(tmax, s[kt][r]);
    tmax = fmaxf(tmax, __shfl_xor(tmax, 16));
    tmax = fmaxf(tmax, __shfl_xor(tmax, 32));
    float mnew = fmaxf(m_run, tmax);
    float alpha = __builtin_amdgcn_exp2f(m_run - mnew);

    float psum = 0.f;
    half4v pf[8];
#pragma unroll
    for (int kt = 0; kt < 8; kt++) {
      float p0 = __builtin_amdgcn_exp2f(s[kt][0] - mnew);
      float p1 = __builtin_amdgcn_exp2f(s[kt][1] - mnew);
      float p2 = __builtin_amdgcn_exp2f(s[kt][2] - mnew);
      float p3 = __builtin_amdgcn_exp2f(s[kt][3] - mnew);
      psum += (p0 + p1) + (p2 + p3);
      half2v pk01 = __builtin_bit_cast(half2v, __builtin_amdgcn_cvt_pkrtz(p0, p1));
      half2v pk23 = __builtin_bit_cast(half2v, __builtin_amdgcn_cvt_pkrtz(p2, p3));
      pf[kt] = __builtin_shufflevector(pk01, pk23, 0, 1, 2, 3);
    }
    psum += __shfl_xor(psum, 16);
    psum += __shfl_xor(psum, 32);
    l_run = l_run * alpha + psum;
    m_run = mnew;
#pragma unroll
    for (int dt = 0; dt < 4; dt++) o[dt] *= alpha;

    // PV: o^T[d][q] += V^T x P, 4 d-tiles x 4 key-groups of 16x16x32.
    // pf[2p] holds P[32p+4q+(0..3)][q], pf[2p+1] holds P[32p+16+4q+(0..3)][q]
    // -> concat is the x32 B-operand (k=8q+j). Matching V^T A-operand:
    // two half4v at d*264 + p*64 + q*8 (+32) -- same addresses round 1 read.
    __builtin_amdgcn_s_setprio(1);
#pragma unroll
    for (int dt = 0; dt < 4; dt++) {
      int d = dt * 16 + l15;
#pragma unroll
      for (int p = 0; p < 4; p++) {
        half4v v0 = *(const half4v*)((char*)Vs + d * 264 + p * 64 + quad * 8);
        half4v v1 = *(const half4v*)((char*)Vs + d * 264 + p * 64 + 32 + quad * 8);
        half8v vf = __builtin_shufflevector(v0, v1, 0, 1, 2, 3, 4, 5, 6, 7);
        half8v pf8 = __builtin_shufflevector(pf[2 * p], pf[2 * p + 1],
                                             0, 1, 2, 3, 4, 5, 6, 7);
        o[dt] = __builtin_amdgcn_mfma_f32_16x16x32_f16(vf, pf8, o[dt], 0, 0, 0);
      }
    }
    __builtin_amdgcn_s_setprio(0);
    __syncthreads();
  }

  float inv = 1.0f / l_run;
#pragma unroll
  for (int dt = 0; dt < 4; dt++) {
    half4v yv;
#pragma unroll
    for (int r = 0; r < 4; r++) yv[r] = (_Float16)(o[dt][r] * inv);
    *(half4v*)(Yh + qoff + dt * 16 + quad * 4) = yv;  // row q, cols h*64+d..
  }
}

// ---------------------------------------------------------------------------
extern "C" void kernel_launch(void* const* d_in, const int* in_sizes, int n_in,
                              void* d_out, int out_size, void* d_ws, size_t ws_size,
                              hipStream_t stream) {
  const float* x  = (const float*)d_in[0];
  const float* Wq = (const float*)d_in[1];
  const float* bq = (const float*)d_in[2];
  const float* Wk = (const float*)d_in[3];
  const float* bk = (const float*)d_in[4];
  const float* Wv = (const float*)d_in[5];
  const float* bv = (const float*)d_in[6];
  const float* Wo = (const float*)d_in[7];
  const float* bo = (const float*)d_in[8];
  float* out = (float*)d_out;

  // Workspace carve-up (bytes). Each f16 plane M_*C_ = 8 MB.
  char* ws = (char*)d_ws;
  _Float16* xh   = (_Float16*)(ws);                        // 8 MB
  _Float16* Qh   = (_Float16*)(ws + (((size_t)8)  << 20)); // 8 MB
  _Float16* Kh   = (_Float16*)(ws + (((size_t)16) << 20)); // 8 MB
  _Float16* Vt   = (_Float16*)(ws + (((size_t)24) << 20)); // 8 MB  [b,h,d,t]
  _Float16* Yh   = (_Float16*)(ws + (((size_t)32) << 20)); // 8 MB
  _Float16* Wt3  = (_Float16*)(ws + (((size_t)40) << 20)); // 6 MB  [3072][1024]
  _Float16* Wot  = (_Float16*)(ws + (((size_t)46) << 20)); // 2 MB  [1024][1024]
  float*    b3   = (float*)   (ws + (((size_t)48) << 20)); // 12 KB

  prep_kernel<<<8204, 256, 0, stream>>>(x, Wq, Wk, Wv, Wo, bq, bk, bv,
                                        xh, Wt3, Wot, b3);

  // Fused QKV projection: [4096,1024] @ [1024,3072] -> Q,K (f16) + V^T (f16).
  gemm_f16_kernel<128, 128, 0, 24, 32><<<dim3(24, 32), 256, 0, stream>>>(
      xh, Wt3, b3, Qh, Kh, Vt, nullptr);

  attn_f16_kernel<<<dim3(T_ / 128, H_, B_), 512, 0, stream>>>(Qh, Kh, Vt, Yh);

  // Output projection: Yh @ Wot^T + bo -> fp32 out.
  gemm_f16_kernel<64, 128, 1, 8, 64><<<dim3(8, 64), 256, 0, stream>>>(
      Yh, Wot, bo, nullptr, nullptr, nullptr, out);
}